// Round 9
// baseline (242.976 us; speedup 1.0000x reference)
//
#include <hip/hip_runtime.h>
#include <hip/hip_bf16.h>
#include <math.h>

typedef __attribute__((ext_vector_type(8))) _Float16 half8;   // 8 x f16 (4 VGPR)
typedef __attribute__((ext_vector_type(2))) _Float16 half2v;
typedef __attribute__((ext_vector_type(4))) float f32x4;      // MFMA acc

#define OBS_X 40.0f
#define OBS_Y 15.0f
#define RADIUS 6.0f
#define TPW 8       // tiles (16 rows each) per wave
#define GRID 1024   // 1024 blocks * 4 waves * TPW * 16 rows = 524288; 4 blocks/CU

__device__ __forceinline__ half2v pkrtz(float a, float b) {
    return __builtin_bit_cast(half2v, __builtin_amdgcn_cvt_pkrtz(a, b));
}

// fp16 hi/lo split of 8 floats (RNE casts)
__device__ __forceinline__ void split8(const float* v, half8& hi, half8& lo) {
#pragma unroll
    for (int j = 0; j < 8; ++j) {
        _Float16 h = (_Float16)v[j];
        hi[j] = h;
        lo[j] = (_Float16)(v[j] - (float)h);
    }
}

// Opaque register pin: the asm "modifies" v, so the compiler can neither
// rematerialize it from memory nor sink its producer into the loop.
__device__ __forceinline__ void pin(half8& v) {
    f32x4 t = __builtin_bit_cast(f32x4, v);
    asm volatile("" : "+v"(t));
    v = __builtin_bit_cast(half8, t);
}

__global__ __launch_bounds__(256, 4) void barriernet_fused(
    const float* __restrict__ x,
    const float* __restrict__ mean_, const float* __restrict__ std_,
    const float* __restrict__ w1,  const float* __restrict__ b1,
    const float* __restrict__ w21, const float* __restrict__ b21,
    const float* __restrict__ w22, const float* __restrict__ b22,
    const float* __restrict__ w31, const float* __restrict__ b31,
    const float* __restrict__ w32, const float* __restrict__ b32,
    float* __restrict__ out)
{
    // smem: [0,32768)      4 per-wave h1 hi/lo planes (XOR-swizzled)
    //       [32768,34816)  w1c_h [128 rows][8]: cols 0-4 = w1 hi, col 5 = b1 hi, 6-7 = 0
    //       [34816,36864)  w1c_l (lo parts)
    //       [36864,36880)  16B zero row (fc1 A-frag for lane group g==3)
    __shared__ unsigned char smem[36880];
    const int tid  = threadIdx.x;
    const int lane = tid & 63;
    const int wv   = tid >> 6;
    const int r16  = lane & 15;     // batch row within tile / MFMA col
    const int g    = lane >> 4;     // lane group 0..3 (k-slice / D-row group)
    unsigned char* h1hi = smem + wv * 8192;             // [16 rows][128 feats] f16, 256B rows
    unsigned char* h1lo = h1hi + 4096;
    const unsigned swz = ((unsigned)(r16 & 7)) << 4;
    const int slot = blockIdx.x * 4 + wv;               // 0..4095

    // ---- one-time: build fc1 concat-A frags in LDS (threads 0-127: one row each) ----
    if (tid < 128) {
        float v[8];
#pragma unroll
        for (int j = 0; j < 5; ++j) v[j] = w1[tid * 5 + j];
        v[5] = b1[tid];                                 // bias as K-column 5
        v[6] = 0.f; v[7] = 0.f;
        half8 hi, lo;
        split8(v, hi, lo);
        *(half8*)(smem + 32768 + tid * 16) = hi;
        *(half8*)(smem + 34816 + tid * 16) = lo;
    }
    if (tid == 128) {
        half8 z = {0,0,0,0,0,0,0,0};
        *(half8*)(smem + 36864) = z;
    }

    // ---- one-time: gather w2cat fragments into registers (128 VGPR, pinned) ----
    // frag lane l holds A[row=l&15][k=(l>>4)*8+j]; tile t covers w2cat rows 16t..16t+15
    half8 w2h[4][4], w2l[4][4];
#pragma unroll
    for (int t = 0; t < 4; ++t) {
        const int r = 16 * t + r16;
        const float* src = (r < 32) ? (w21 + r * 128) : (w22 + (r - 32) * 128);
#pragma unroll
        for (int kc = 0; kc < 4; ++kc) {
            const float4 f0 = *(const float4*)(src + kc * 32 + g * 8);
            const float4 f1 = *(const float4*)(src + kc * 32 + g * 8 + 4);
            float v[8];
            v[0] = f0.x; v[1] = f0.y; v[2] = f0.z; v[3] = f0.w;
            v[4] = f1.x; v[5] = f1.y; v[6] = f1.z; v[7] = f1.w;
            split8(v, w2h[t][kc], w2l[t][kc]);
            pin(w2h[t][kc]);
            pin(w2l[t][kc]);
        }
    }

    __syncthreads();    // w1c LDS ready; only barrier in the kernel

    // hoisted uniform scalars (SGPR)
    const float m0 = mean_[0], m1 = mean_[1], m2 = mean_[2], m3 = mean_[3];
    const float sd0 = std_[0], sd1 = std_[1], sd2 = std_[2], sd3 = std_[3];
    const float bb31_0 = b31[0], bb31_1 = b31[1], bb32_0 = b32[0], bb32_1 = b32[1];

    // fc1 A-frag LDS byte offset for this lane (g<2: hi row, g==2: lo row, g==3: zeros)
    const unsigned awbase = (g < 2) ? 32768u : ((g == 2) ? 34816u : 36864u);
    const unsigned awstep = (g == 3) ? 0u : 16u;        // zero row is not indexed by fr

    // ---- x prefetch for tile 0 (all lanes load row r16: quad-broadcast) ----
    float xa0, xa1, xa2, xa3, xa4;
    {
        const float* xr = x + (size_t)(slot * TPW * 16 + r16) * 5;
        xa0 = xr[0]; xa1 = xr[1]; xa2 = xr[2]; xa3 = xr[3]; xa4 = xr[4];
    }

#pragma unroll 1
    for (int it = 0; it < TPW; ++it) {
        const int rowbase = (slot * TPW + it) * 16;

        // ---- build fc1 concat B-frag: [xh(5),1 | xl(5),0 | xh(5),1 | 0] over k-groups ----
        half8 bx = {0,0,0,0,0,0,0,0};
        {
            float xs[5] = {xa0, xa1, xa2, xa3, xa4};
            const bool useL = (g == 1), useZ = (g == 3);
#pragma unroll
            for (int j = 0; j < 5; ++j) {
                _Float16 h = (_Float16)xs[j];
                _Float16 l = (_Float16)(xs[j] - (float)h);
                bx[j] = useZ ? (_Float16)0.f : (useL ? l : h);
            }
            bx[5] = (useZ || useL) ? (_Float16)0.f : (_Float16)1.0f;
        }
        const float xc0 = xa0, xc1 = xa1, xc2 = xa2, xc3 = xa3;  // for epilogue

        // prefetch next tile's x (latency hides under fc1/fc2)
        if (it + 1 < TPW) {
            const float* xr = x + (size_t)(rowbase + 16 + r16) * 5;
            xa0 = xr[0]; xa1 = xr[1]; xa2 = xr[2]; xa3 = xr[3]; xa4 = xr[4];
        }

        // ---- fc1 = relu(W1'[x;1]^T): ONE MFMA per 16-feat block (3 split terms in K) ----
#pragma unroll
        for (int t8 = 0; t8 < 8; ++t8) {
            const int fr = t8 * 16 + r16;
            const half8 aw = *(const half8*)(smem + awbase + (unsigned)fr * awstep);
            f32x4 acc = {0.f, 0.f, 0.f, 0.f};
            acc = __builtin_amdgcn_mfma_f32_16x16x32_f16(aw, bx, acc, 0, 0, 0);
            float v0 = fmaxf(acc[0], 0.f), v1 = fmaxf(acc[1], 0.f);
            float v2 = fmaxf(acc[2], 0.f), v3 = fmaxf(acc[3], 0.f);
            half2v hA = pkrtz(v0, v1);
            half2v hB = pkrtz(v2, v3);
            half2v lA = pkrtz(v0 - (float)hA[0], v1 - (float)hA[1]);
            half2v lB = pkrtz(v2 - (float)hB[0], v3 - (float)hB[1]);
            const unsigned off = ((unsigned)(32 * t8 + 8 * g)) ^ swz;
            uint2 ph; ph.x = __builtin_bit_cast(unsigned, hA); ph.y = __builtin_bit_cast(unsigned, hB);
            uint2 pl; pl.x = __builtin_bit_cast(unsigned, lA); pl.y = __builtin_bit_cast(unsigned, lB);
            *(uint2*)(h1hi + r16 * 256 + off) = ph;
            *(uint2*)(h1lo + r16 * 256 + off) = pl;
        }

        asm volatile("" ::: "memory");   // forbid IR reorder of LDS write->read across type-puns

        // ---- fc2cat: D[out 16t+4g+r][batch r16] = W2cat(A,reg) @ h1(B,LDS), fp16x3 ----
        half8 ah[4], al[4];
#pragma unroll
        for (int kc = 0; kc < 4; ++kc) {
            const unsigned off = ((unsigned)(kc * 64 + g * 16)) ^ swz;
            ah[kc] = *(const half8*)(h1hi + r16 * 256 + off);
            al[kc] = *(const half8*)(h1lo + r16 * 256 + off);
        }
        f32x4 acc2[4];
#pragma unroll
        for (int t = 0; t < 4; ++t) {
            const float4 bb2 = (t < 2) ? *(const float4*)(b21 + 16 * t + 4 * g)
                                       : *(const float4*)(b22 + 16 * (t - 2) + 4 * g);
            f32x4 a = {bb2.x, bb2.y, bb2.z, bb2.w};
#pragma unroll
            for (int kc = 0; kc < 4; ++kc) {
                a = __builtin_amdgcn_mfma_f32_16x16x32_f16(w2h[t][kc], al[kc], a, 0, 0, 0);
                a = __builtin_amdgcn_mfma_f32_16x16x32_f16(w2l[t][kc], ah[kc], a, 0, 0, 0);
                a = __builtin_amdgcn_mfma_f32_16x16x32_f16(w2h[t][kc], ah[kc], a, 0, 0, 0);
            }
            acc2[t] = a;
        }

        asm volatile("" ::: "memory");   // forbid next-iter LDS writes moving above these reads

        // ---- heads: per-lane partials over outs {16t+4g+r}, reduce over g (2 shfls) ----
        const f32x4 wA0 = *(const f32x4*)(w31 + 4 * g);       // x31 row0, x21 inputs 0-15
        const f32x4 wA1 = *(const f32x4*)(w31 + 16 + 4 * g);  //           x21 inputs 16-31
        const f32x4 wB0 = *(const f32x4*)(w31 + 32 + 4 * g);  // x31 row1
        const f32x4 wB1 = *(const f32x4*)(w31 + 48 + 4 * g);
        const f32x4 wC0 = *(const f32x4*)(w32 + 4 * g);       // x32 row0
        const f32x4 wC1 = *(const f32x4*)(w32 + 16 + 4 * g);
        const f32x4 wD0 = *(const f32x4*)(w32 + 32 + 4 * g);  // x32 row1
        const f32x4 wD1 = *(const f32x4*)(w32 + 48 + 4 * g);
        float p0 = 0.f, p1 = 0.f, p2 = 0.f, p3 = 0.f;
#pragma unroll
        for (int r = 0; r < 4; ++r) {
            float v0 = fmaxf(acc2[0][r], 0.f), v1 = fmaxf(acc2[1][r], 0.f);
            float v2 = fmaxf(acc2[2][r], 0.f), v3 = fmaxf(acc2[3][r], 0.f);
            p0 += wA0[r] * v0 + wA1[r] * v1;
            p1 += wB0[r] * v0 + wB1[r] * v1;
            p2 += wC0[r] * v2 + wC1[r] * v3;
            p3 += wD0[r] * v2 + wD1[r] * v3;
        }
        p0 += __shfl_xor(p0, 16); p0 += __shfl_xor(p0, 32);
        p1 += __shfl_xor(p1, 16); p1 += __shfl_xor(p1, 32);
        p2 += __shfl_xor(p2, 16); p2 += __shfl_xor(p2, 32);
        p3 += __shfl_xor(p3, 16); p3 += __shfl_xor(p3, 32);

        // ---- physics epilogue on lanes 0-15 (batch = r16) ----
        if (lane < 16) {
            const float a31_0 = p0 + bb31_0, a31_1 = p1 + bb31_1;
            const float a32_0 = p2 + bb32_0, a32_1 = p3 + bb32_1;
            const float s0 = 4.0f / (1.0f + __expf(-a32_0));
            const float s1 = 4.0f / (1.0f + __expf(-a32_1));
            const float px = fmaf(xc0, sd0, m0);
            const float py = fmaf(xc1, sd1, m1);
            const float th = fmaf(xc2, sd2, m2);
            const float v  = fmaf(xc3, sd3, m3);
            float sn, cs; __sincosf(th, &sn, &cs);
            const float dx = px - OBS_X, dy = py - OBS_Y;
            const float barrier     = dx * dx + dy * dy - RADIUS * RADIUS;
            const float barrier_dot = 2.f * dx * v * cs + 2.f * dy * v * sn;
            const float Lf2b = 2.f * v * v;
            const float G0 = 2.f * dx * v * sn - 2.f * dy * v * cs;   // -LgLfbu1
            const float G1 = -(2.f * dx * cs + 2.f * dy * sn);        // -LgLfbu2
            const float h  = Lf2b + (s0 + s1) * barrier_dot + s0 * s1 * barrier;
            const float u00 = -a31_0, u01 = -a31_1;
            const float viol = G0 * u00 + G1 * u01 - h;
            const float gg   = G0 * G0 + G1 * G1;
            const float lam  = fmaxf(viol, 0.f) / (gg + 1e-12f);
            float2 uo = make_float2(fmaf(-lam, G0, u00), fmaf(-lam, G1, u01));
            ((float2*)out)[rowbase + r16] = uo;
        }
    }
}

extern "C" void kernel_launch(void* const* d_in, const int* in_sizes, int n_in,
                              void* d_out, int out_size, void* d_ws, size_t ws_size,
                              hipStream_t stream) {
    const float* x     = (const float*)d_in[0];
    // d_in[1] = sgn (unused by the reference computation)
    const float* mean_ = (const float*)d_in[2];
    const float* std_  = (const float*)d_in[3];
    const float* w1    = (const float*)d_in[4];
    const float* b1    = (const float*)d_in[5];
    const float* w21   = (const float*)d_in[6];
    const float* b21   = (const float*)d_in[7];
    const float* w22   = (const float*)d_in[8];
    const float* b22   = (const float*)d_in[9];
    const float* w31   = (const float*)d_in[10];
    const float* b31   = (const float*)d_in[11];
    const float* w32   = (const float*)d_in[12];
    const float* b32   = (const float*)d_in[13];

    barriernet_fused<<<GRID, 256, 0, stream>>>(
        x, mean_, std_, w1, b1, w21, b21, w22, b22, w31, b31, w32, b32,
        (float*)d_out);
}

// Round 10
// 137.408 us; speedup vs baseline: 1.7683x; 1.7683x over previous
//
#include <hip/hip_runtime.h>
#include <hip/hip_bf16.h>
#include <math.h>

typedef __attribute__((ext_vector_type(8))) _Float16 half8;   // 8 x f16 (4 VGPR)
typedef __attribute__((ext_vector_type(2))) _Float16 half2v;
typedef __attribute__((ext_vector_type(4))) float f32x4;      // MFMA acc

#define OBS_X 40.0f
#define OBS_Y 15.0f
#define RADIUS 6.0f
#define TPW 16      // tiles (16 rows each) per wave
#define GRID 512    // 512 blocks * 4 waves * TPW * 16 rows = 524288; 2 blocks/CU

__device__ __forceinline__ half2v pkrtz(float a, float b) {
    return __builtin_bit_cast(half2v, __builtin_amdgcn_cvt_pkrtz(a, b));
}

// fp16 hi/lo split of 8 floats (RNE casts)
__device__ __forceinline__ void split8(const float* v, half8& hi, half8& lo) {
#pragma unroll
    for (int j = 0; j < 8; ++j) {
        _Float16 h = (_Float16)v[j];
        hi[j] = h;
        lo[j] = (_Float16)(v[j] - (float)h);
    }
}

// Opaque register pin
__device__ __forceinline__ void pin(half8& v) {
    f32x4 t = __builtin_bit_cast(f32x4, v);
    asm volatile("" : "+v"(t));
    v = __builtin_bit_cast(half8, t);
}

// LDS map (bytes):
//   [0,65536)       4 waves x double-buffered h1: wv*16384 + buf*8192 (hi 4K + lo 4K)
//   [65536,67584)   w1c_h [128 rows][16B]: w1 hi cols0-4, b1 hi col5, 0 pad
//   [67584,69632)   w1c_l (lo parts)
//   [69632,69648)   16B zero row (fc1 A-frag for lane group g==3)
__global__ __launch_bounds__(256, 2) void barriernet_fused(
    const float* __restrict__ x,
    const float* __restrict__ mean_, const float* __restrict__ std_,
    const float* __restrict__ w1,  const float* __restrict__ b1,
    const float* __restrict__ w21, const float* __restrict__ b21,
    const float* __restrict__ w22, const float* __restrict__ b22,
    const float* __restrict__ w31, const float* __restrict__ b31,
    const float* __restrict__ w32, const float* __restrict__ b32,
    float* __restrict__ out)
{
    __shared__ unsigned char smem[69648];
    const int tid  = threadIdx.x;
    const int lane = tid & 63;
    const int wv   = tid >> 6;
    const int r16  = lane & 15;     // batch row within tile / MFMA col
    const int g    = lane >> 4;     // lane group 0..3
    unsigned char* h1base = smem + wv * 16384;
    const unsigned swz = ((unsigned)(r16 & 7)) << 4;
    const int slot = blockIdx.x * 4 + wv;               // 0..2047

    // ---- one-time: build fc1 concat-A frags in LDS ----
    if (tid < 128) {
        float v[8];
#pragma unroll
        for (int j = 0; j < 5; ++j) v[j] = w1[tid * 5 + j];
        v[5] = b1[tid];
        v[6] = 0.f; v[7] = 0.f;
        half8 hi, lo;
        split8(v, hi, lo);
        *(half8*)(smem + 65536 + tid * 16) = hi;
        *(half8*)(smem + 67584 + tid * 16) = lo;
    }
    if (tid == 128) {
        half8 z = {0,0,0,0,0,0,0,0};
        *(half8*)(smem + 69632) = z;
    }

    // ---- one-time: gather w2cat fragments into pinned registers (128 regs) ----
    half8 w2h[4][4], w2l[4][4];
#pragma unroll
    for (int t = 0; t < 4; ++t) {
        const int r = 16 * t + r16;
        const float* src = (r < 32) ? (w21 + r * 128) : (w22 + (r - 32) * 128);
#pragma unroll
        for (int kc = 0; kc < 4; ++kc) {
            const float4 f0 = *(const float4*)(src + kc * 32 + g * 8);
            const float4 f1 = *(const float4*)(src + kc * 32 + g * 8 + 4);
            float v[8];
            v[0] = f0.x; v[1] = f0.y; v[2] = f0.z; v[3] = f0.w;
            v[4] = f1.x; v[5] = f1.y; v[6] = f1.z; v[7] = f1.w;
            split8(v, w2h[t][kc], w2l[t][kc]);
            pin(w2h[t][kc]);
            pin(w2l[t][kc]);
        }
    }

    __syncthreads();    // w1c LDS ready; only block barrier in the kernel

    // hoisted uniform scalars (SGPR)
    const float m0 = mean_[0], m1 = mean_[1], m2 = mean_[2], m3 = mean_[3];
    const float sd0 = std_[0], sd1 = std_[1], sd2 = std_[2], sd3 = std_[3];
    const float bb31_0 = b31[0], bb31_1 = b31[1], bb32_0 = b32[0], bb32_1 = b32[1];

    // fc1 A-frag base (g<2: hi rows, g==2: lo rows, g==3: zero row)
    const unsigned awbase = (g < 2) ? 65536u : ((g == 2) ? 67584u : 69632u);
    const unsigned awstep = (g == 3) ? 0u : 16u;

    // fc1 into buffer b from frag bx (macro to keep codegen identical across uses)
#define FC1_TO(BUF, BX)                                                               \
    {                                                                                 \
        unsigned char* hhi = h1base + ((unsigned)(BUF) << 13);                        \
        unsigned char* hlo = hhi + 4096;                                              \
        _Pragma("unroll")                                                             \
        for (int t8 = 0; t8 < 8; ++t8) {                                              \
            const int fr = t8 * 16 + r16;                                             \
            const half8 aw = *(const half8*)(smem + awbase + (unsigned)fr * awstep);  \
            f32x4 acc = {0.f, 0.f, 0.f, 0.f};                                         \
            acc = __builtin_amdgcn_mfma_f32_16x16x32_f16(aw, BX, acc, 0, 0, 0);       \
            float v0 = fmaxf(acc[0], 0.f), v1 = fmaxf(acc[1], 0.f);                   \
            float v2 = fmaxf(acc[2], 0.f), v3 = fmaxf(acc[3], 0.f);                   \
            half2v hA = pkrtz(v0, v1);                                                \
            half2v hB = pkrtz(v2, v3);                                                \
            half2v lA = pkrtz(v0 - (float)hA[0], v1 - (float)hA[1]);                  \
            half2v lB = pkrtz(v2 - (float)hB[0], v3 - (float)hB[1]);                  \
            const unsigned off = ((unsigned)(32 * t8 + 8 * g)) ^ swz;                 \
            uint2 ph; ph.x = __builtin_bit_cast(unsigned, hA);                        \
            ph.y = __builtin_bit_cast(unsigned, hB);                                  \
            uint2 pl; pl.x = __builtin_bit_cast(unsigned, lA);                        \
            pl.y = __builtin_bit_cast(unsigned, lB);                                  \
            *(uint2*)(hhi + r16 * 256 + off) = ph;                                    \
            *(uint2*)(hlo + r16 * 256 + off) = pl;                                    \
        }                                                                             \
    }

    // build fc1 concat B-frag from 5 x values: [xh,1 | xl,0 | xh,1 | 0] across g
#define BUILD_BX(DST, X0, X1, X2, X3, X4)                                             \
    {                                                                                 \
        float xs[5] = {X0, X1, X2, X3, X4};                                           \
        const bool useL = (g == 1), useZ = (g == 3);                                  \
        _Pragma("unroll")                                                             \
        for (int j = 0; j < 5; ++j) {                                                 \
            _Float16 h = (_Float16)xs[j];                                             \
            _Float16 l = (_Float16)(xs[j] - (float)h);                                \
            DST[j] = useZ ? (_Float16)0.f : (useL ? l : h);                           \
        }                                                                             \
        DST[5] = (useZ || useL) ? (_Float16)0.f : (_Float16)1.0f;                     \
        DST[6] = (_Float16)0.f; DST[7] = (_Float16)0.f;                               \
    }

    // ---- prologue: x(0) -> fc1 -> buf0; prefetch x(1) ----
    float xa0, xa1, xa2, xa3, xa4;
    {
        const float* xr = x + (size_t)(slot * TPW * 16 + r16) * 5;
        xa0 = xr[0]; xa1 = xr[1]; xa2 = xr[2]; xa3 = xr[3]; xa4 = xr[4];
    }
    float xc0 = xa0, xc1 = xa1, xc2 = xa2, xc3 = xa3;   // epilogue x for tile 0
    {
        half8 bx0;
        BUILD_BX(bx0, xa0, xa1, xa2, xa3, xa4);
        FC1_TO(0, bx0);
    }
    {
        const float* xr = x + (size_t)(slot * TPW * 16 + 16 + r16) * 5;
        xa0 = xr[0]; xa1 = xr[1]; xa2 = xr[2]; xa3 = xr[3]; xa4 = xr[4];
    }

#pragma unroll 1
    for (int it = 0; it < TPW; ++it) {
        const int cur = it & 1;
        const int rowbase = (slot * TPW + it) * 16;
        unsigned char* bhi = h1base + ((unsigned)cur << 13);
        unsigned char* blo = bhi + 4096;

        asm volatile("" ::: "memory");   // iteration boundary: prior writes before these reads

        // ---- issue fc2 reads for tile `it` EARLY (latency hides under fc1 below) ----
        half8 ah[4], al[4];
#pragma unroll
        for (int kc = 0; kc < 4; ++kc) {
            const unsigned off = ((unsigned)(kc * 64 + g * 16)) ^ swz;
            ah[kc] = *(const half8*)(bhi + r16 * 256 + off);
            al[kc] = *(const half8*)(blo + r16 * 256 + off);
        }

        // ---- fc1 for tile it+1 into the other buffer (overlaps with reads above) ----
        float xn0 = xc0, xn1 = xc1, xn2 = xc2, xn3 = xc3;
        if (it + 1 < TPW) {
            xn0 = xa0; xn1 = xa1; xn2 = xa2; xn3 = xa3;
            half8 bxn;
            BUILD_BX(bxn, xa0, xa1, xa2, xa3, xa4);
            if (it + 2 < TPW) {
                const float* xr = x + (size_t)(rowbase + 32 + r16) * 5;
                xa0 = xr[0]; xa1 = xr[1]; xa2 = xr[2]; xa3 = xr[3]; xa4 = xr[4];
            }
            FC1_TO(cur ^ 1, bxn);
        }

        // ---- fc2cat for tile it: D[out 16t+4g+r][batch r16], fp16x3 ----
        f32x4 acc2[4];
#pragma unroll
        for (int t = 0; t < 4; ++t) {
            const float4 bb2 = (t < 2) ? *(const float4*)(b21 + 16 * t + 4 * g)
                                       : *(const float4*)(b22 + 16 * (t - 2) + 4 * g);
            f32x4 a = {bb2.x, bb2.y, bb2.z, bb2.w};
#pragma unroll
            for (int kc = 0; kc < 4; ++kc) {
                a = __builtin_amdgcn_mfma_f32_16x16x32_f16(w2h[t][kc], al[kc], a, 0, 0, 0);
                a = __builtin_amdgcn_mfma_f32_16x16x32_f16(w2l[t][kc], ah[kc], a, 0, 0, 0);
                a = __builtin_amdgcn_mfma_f32_16x16x32_f16(w2h[t][kc], ah[kc], a, 0, 0, 0);
            }
            acc2[t] = a;
        }

        // ---- heads: per-lane partials over outs {16t+4g+r}, reduce over g ----
        const f32x4 wA0 = *(const f32x4*)(w31 + 4 * g);
        const f32x4 wA1 = *(const f32x4*)(w31 + 16 + 4 * g);
        const f32x4 wB0 = *(const f32x4*)(w31 + 32 + 4 * g);
        const f32x4 wB1 = *(const f32x4*)(w31 + 48 + 4 * g);
        const f32x4 wC0 = *(const f32x4*)(w32 + 4 * g);
        const f32x4 wC1 = *(const f32x4*)(w32 + 16 + 4 * g);
        const f32x4 wD0 = *(const f32x4*)(w32 + 32 + 4 * g);
        const f32x4 wD1 = *(const f32x4*)(w32 + 48 + 4 * g);
        float p0 = 0.f, p1 = 0.f, p2 = 0.f, p3 = 0.f;
#pragma unroll
        for (int r = 0; r < 4; ++r) {
            float v0 = fmaxf(acc2[0][r], 0.f), v1 = fmaxf(acc2[1][r], 0.f);
            float v2 = fmaxf(acc2[2][r], 0.f), v3 = fmaxf(acc2[3][r], 0.f);
            p0 += wA0[r] * v0 + wA1[r] * v1;
            p1 += wB0[r] * v0 + wB1[r] * v1;
            p2 += wC0[r] * v2 + wC1[r] * v3;
            p3 += wD0[r] * v2 + wD1[r] * v3;
        }
        p0 += __shfl_xor(p0, 16); p0 += __shfl_xor(p0, 32);
        p1 += __shfl_xor(p1, 16); p1 += __shfl_xor(p1, 32);
        p2 += __shfl_xor(p2, 16); p2 += __shfl_xor(p2, 32);
        p3 += __shfl_xor(p3, 16); p3 += __shfl_xor(p3, 32);

        // ---- physics epilogue on lanes 0-15 (batch = r16) for tile it ----
        if (lane < 16) {
            const float a31_0 = p0 + bb31_0, a31_1 = p1 + bb31_1;
            const float a32_0 = p2 + bb32_0, a32_1 = p3 + bb32_1;
            const float s0 = 4.0f / (1.0f + __expf(-a32_0));
            const float s1 = 4.0f / (1.0f + __expf(-a32_1));
            const float px = fmaf(xc0, sd0, m0);
            const float py = fmaf(xc1, sd1, m1);
            const float th = fmaf(xc2, sd2, m2);
            const float v  = fmaf(xc3, sd3, m3);
            float sn, cs; __sincosf(th, &sn, &cs);
            const float dx = px - OBS_X, dy = py - OBS_Y;
            const float barrier     = dx * dx + dy * dy - RADIUS * RADIUS;
            const float barrier_dot = 2.f * dx * v * cs + 2.f * dy * v * sn;
            const float Lf2b = 2.f * v * v;
            const float G0 = 2.f * dx * v * sn - 2.f * dy * v * cs;   // -LgLfbu1
            const float G1 = -(2.f * dx * cs + 2.f * dy * sn);        // -LgLfbu2
            const float h  = Lf2b + (s0 + s1) * barrier_dot + s0 * s1 * barrier;
            const float u00 = -a31_0, u01 = -a31_1;
            const float viol = G0 * u00 + G1 * u01 - h;
            const float gg   = G0 * G0 + G1 * G1;
            const float lam  = fmaxf(viol, 0.f) / (gg + 1e-12f);
            float2 uo = make_float2(fmaf(-lam, G0, u00), fmaf(-lam, G1, u01));
            ((float2*)out)[rowbase + r16] = uo;
        }

        xc0 = xn0; xc1 = xn1; xc2 = xn2; xc3 = xn3;
    }
#undef FC1_TO
#undef BUILD_BX
}

extern "C" void kernel_launch(void* const* d_in, const int* in_sizes, int n_in,
                              void* d_out, int out_size, void* d_ws, size_t ws_size,
                              hipStream_t stream) {
    const float* x     = (const float*)d_in[0];
    // d_in[1] = sgn (unused by the reference computation)
    const float* mean_ = (const float*)d_in[2];
    const float* std_  = (const float*)d_in[3];
    const float* w1    = (const float*)d_in[4];
    const float* b1    = (const float*)d_in[5];
    const float* w21   = (const float*)d_in[6];
    const float* b21   = (const float*)d_in[7];
    const float* w22   = (const float*)d_in[8];
    const float* b22   = (const float*)d_in[9];
    const float* w31   = (const float*)d_in[10];
    const float* b31   = (const float*)d_in[11];
    const float* w32   = (const float*)d_in[12];
    const float* b32   = (const float*)d_in[13];

    barriernet_fused<<<GRID, 256, 0, stream>>>(
        x, mean_, std_, w1, b1, w21, b21, w22, b22, w31, b31, w32, b32,
        (float*)d_out);
}

// Round 12
// 128.324 us; speedup vs baseline: 1.8935x; 1.0708x over previous
//
#include <hip/hip_runtime.h>
#include <hip/hip_bf16.h>
#include <math.h>

typedef __attribute__((ext_vector_type(8))) _Float16 half8;   // 8 x f16 (4 VGPR)
typedef __attribute__((ext_vector_type(2))) _Float16 half2v;
typedef __attribute__((ext_vector_type(4))) float f32x4;      // MFMA acc

#define OBS_X 40.0f
#define OBS_Y 15.0f
#define RADIUS 6.0f
#define MPB 8       // 64-row macro-tiles per block
#define GRID 1024   // 1024 blocks * MPB * 64 rows = 524288

__device__ __forceinline__ half2v pkrtz(float a, float b) {
    return __builtin_bit_cast(half2v, __builtin_amdgcn_cvt_pkrtz(a, b));
}

// fp16 hi/lo split of 8 floats (RNE casts)
__device__ __forceinline__ void split8(const float* v, half8& hi, half8& lo) {
#pragma unroll
    for (int j = 0; j < 8; ++j) {
        _Float16 h = (_Float16)v[j];
        hi[j] = h;
        lo[j] = (_Float16)(v[j] - (float)h);
    }
}

// Opaque register pin
__device__ __forceinline__ void pin(half8& v) {
    f32x4 t = __builtin_bit_cast(f32x4, v);
    asm volatile("" : "+v"(t));
    v = __builtin_bit_cast(half8, t);
}

// LDS map (bytes):
//   [0,16384)       h1 hi plane: [64 rows][128 feats] f16, 256B rows, XOR-swizzled
//   [16384,32768)   h1 lo plane
//   [32768,34816)   head stage: [64 batch][4 waves][2 floats] (32 B rows)
//   [34816,36864)   w1c_h [128 rows][16B]: w1 hi cols0-4, b1 hi col5, 0 pad
//   [36864,38912)   w1c_l (lo parts)
//   [38912,38928)   16B zero row (fc1 A-frag for lane group g==3)
__global__ __launch_bounds__(256, 3) void barriernet_fused(
    const float* __restrict__ x,
    const float* __restrict__ mean_, const float* __restrict__ std_,
    const float* __restrict__ w1,  const float* __restrict__ b1,
    const float* __restrict__ w21, const float* __restrict__ b21,
    const float* __restrict__ w22, const float* __restrict__ b22,
    const float* __restrict__ w31, const float* __restrict__ b31,
    const float* __restrict__ w32, const float* __restrict__ b32,
    float* __restrict__ out)
{
    __shared__ unsigned char smem[38928];
    const int tid  = threadIdx.x;
    const int lane = tid & 63;
    const int wv   = tid >> 6;      // wave = out-quarter owner + batch-slice owner
    const int r16  = lane & 15;     // batch col within 16-group / out row within tile
    const int g    = lane >> 4;     // lane group 0..3
    const unsigned swz = ((unsigned)(r16 & 7)) << 4;
    float* stage = (float*)(smem + 32768);

    // ---- one-time: build fc1 concat-A frags in LDS ----
    if (tid < 128) {
        float v[8];
#pragma unroll
        for (int j = 0; j < 5; ++j) v[j] = w1[tid * 5 + j];
        v[5] = b1[tid];                                 // bias as K-column 5
        v[6] = 0.f; v[7] = 0.f;
        half8 hi, lo;
        split8(v, hi, lo);
        *(half8*)(smem + 34816 + tid * 16) = hi;
        *(half8*)(smem + 36864 + tid * 16) = lo;
    }
    if (tid == 128) {
        half8 z = {0,0,0,0,0,0,0,0};
        *(half8*)(smem + 38912) = z;
    }

    // ---- one-time: this wave's w2 OUT-QUARTER into pinned registers (32 regs) ----
    // A-frag lane l holds w2cat[out = 16*wv + (l&15)][k = kc*32 + (l>>4)*8 + j]
    half8 w2h[4], w2l[4];
    {
        const int orow = wv * 16 + r16;
        const float* src = (orow < 32) ? (w21 + orow * 128) : (w22 + (orow - 32) * 128);
#pragma unroll
        for (int kc = 0; kc < 4; ++kc) {
            const float4 f0 = *(const float4*)(src + kc * 32 + g * 8);
            const float4 f1 = *(const float4*)(src + kc * 32 + g * 8 + 4);
            float v[8];
            v[0] = f0.x; v[1] = f0.y; v[2] = f0.z; v[3] = f0.w;
            v[4] = f1.x; v[5] = f1.y; v[6] = f1.z; v[7] = f1.w;
            split8(v, w2h[kc], w2l[kc]);
            pin(w2h[kc]);
            pin(w2l[kc]);
        }
    }

    __syncthreads();    // weight LDS regions ready

    // hoisted uniform scalars (SGPR)
    const float m0 = mean_[0], m1 = mean_[1], m2 = mean_[2], m3 = mean_[3];
    const float sd0 = std_[0], sd1 = std_[1], sd2 = std_[2], sd3 = std_[3];
    const float bb31_0 = b31[0], bb31_1 = b31[1], bb32_0 = b32[0], bb32_1 = b32[1];

    // per-lane persistent: fc2 bias + this wave's head-weight rows (outs 16wv+4g+r)
    const float4 bbv = (wv < 2) ? *(const float4*)(b21 + 16 * wv + 4 * g)
                                : *(const float4*)(b22 + 16 * (wv - 2) + 4 * g);
    const float* hw = (wv < 2) ? w31 : w32;
    const int hoff = (wv < 2) ? 16 * wv : 16 * (wv - 2);
    const f32x4 wH0 = *(const f32x4*)(hw + hoff + 4 * g);        // head row 0
    const f32x4 wH1 = *(const f32x4*)(hw + 32 + hoff + 4 * g);   // head row 1

    // fc1 A-frag base (g<2: hi rows, g==2: lo rows, g==3: zero row)
    const unsigned awbase = (g < 2) ? 34816u : ((g == 2) ? 36864u : 38912u);
    const unsigned awstep = (g == 3) ? 0u : 16u;

    const int slot0 = blockIdx.x * MPB;

    // ---- x prefetch for macro 0 (all lanes load this wave's batch row r16) ----
    float xa0, xa1, xa2, xa3, xa4;
    {
        const float* xr = x + (size_t)(slot0 * 64 + wv * 16 + r16) * 5;
        xa0 = xr[0]; xa1 = xr[1]; xa2 = xr[2]; xa3 = xr[3]; xa4 = xr[4];
    }

#pragma unroll 1
    for (int i = 0; i < MPB; ++i) {
        const int rowbase = (slot0 + i) * 64;
        const int hrow = wv * 16 + r16;     // this lane's h1 row (its batch)

        // ---- build fc1 concat B-frag: [xh(5),1 | xl(5),0 | xh(5),1 | 0] over k-groups ----
        half8 bx = {0,0,0,0,0,0,0,0};
        {
            float xs[5] = {xa0, xa1, xa2, xa3, xa4};
            const bool useL = (g == 1), useZ = (g == 3);
#pragma unroll
            for (int j = 0; j < 5; ++j) {
                _Float16 h = (_Float16)xs[j];
                _Float16 l = (_Float16)(xs[j] - (float)h);
                bx[j] = useZ ? (_Float16)0.f : (useL ? l : h);
            }
            bx[5] = (useZ || useL) ? (_Float16)0.f : (_Float16)1.0f;
        }
        const float xc0 = xa0, xc1 = xa1, xc2 = xa2, xc3 = xa3;  // for epilogue

        // prefetch next macro's x
        if (i + 1 < MPB) {
            const float* xr = x + (size_t)(rowbase + 64 + wv * 16 + r16) * 5;
            xa0 = xr[0]; xa1 = xr[1]; xa2 = xr[2]; xa3 = xr[3]; xa4 = xr[4];
        }

        // ---- fc1 = relu(W1'[x;1]^T) for this wave's 16-row slice into shared h1 ----
#pragma unroll
        for (int t8 = 0; t8 < 8; ++t8) {
            const int fr = t8 * 16 + r16;
            const half8 aw = *(const half8*)(smem + awbase + (unsigned)fr * awstep);
            f32x4 acc = {0.f, 0.f, 0.f, 0.f};
            acc = __builtin_amdgcn_mfma_f32_16x16x32_f16(aw, bx, acc, 0, 0, 0);
            float v0 = fmaxf(acc[0], 0.f), v1 = fmaxf(acc[1], 0.f);
            float v2 = fmaxf(acc[2], 0.f), v3 = fmaxf(acc[3], 0.f);
            half2v hA = pkrtz(v0, v1);
            half2v hB = pkrtz(v2, v3);
            half2v lA = pkrtz(v0 - (float)hA[0], v1 - (float)hA[1]);
            half2v lB = pkrtz(v2 - (float)hB[0], v3 - (float)hB[1]);
            const unsigned off = ((unsigned)(32 * t8 + 8 * g)) ^ swz;
            uint2 ph; ph.x = __builtin_bit_cast(unsigned, hA); ph.y = __builtin_bit_cast(unsigned, hB);
            uint2 pl; pl.x = __builtin_bit_cast(unsigned, lA); pl.y = __builtin_bit_cast(unsigned, lB);
            *(uint2*)(smem + hrow * 256 + off) = ph;
            *(uint2*)(smem + 16384 + hrow * 256 + off) = pl;
        }

        __syncthreads();    // h1 complete (all 64 rows)

        // ---- fc2 (this wave's 16 outs x all 64 batches) + head partials + stage ----
#pragma unroll
        for (int bg = 0; bg < 4; ++bg) {
            f32x4 a = {bbv.x, bbv.y, bbv.z, bbv.w};
            const unsigned brow = (unsigned)(16 * bg + r16) * 256u;
#pragma unroll
            for (int kc = 0; kc < 4; ++kc) {
                const unsigned off = ((unsigned)(kc * 64 + g * 16)) ^ swz;
                const half8 bh = *(const half8*)(smem + brow + off);
                const half8 bl = *(const half8*)(smem + 16384 + brow + off);
                a = __builtin_amdgcn_mfma_f32_16x16x32_f16(w2h[kc], bh, a, 0, 0, 0);
                a = __builtin_amdgcn_mfma_f32_16x16x32_f16(w2h[kc], bl, a, 0, 0, 0);
                a = __builtin_amdgcn_mfma_f32_16x16x32_f16(w2l[kc], bh, a, 0, 0, 0);
            }
            const float v0 = fmaxf(a[0], 0.f), v1 = fmaxf(a[1], 0.f);
            const float v2 = fmaxf(a[2], 0.f), v3 = fmaxf(a[3], 0.f);
            float pA = wH0[0] * v0 + wH0[1] * v1 + wH0[2] * v2 + wH0[3] * v3;
            float pB = wH1[0] * v0 + wH1[1] * v1 + wH1[2] * v2 + wH1[3] * v3;
            pA += __shfl_xor(pA, 16); pA += __shfl_xor(pA, 32);
            pB += __shfl_xor(pB, 16); pB += __shfl_xor(pB, 32);
            if (g == 0)
                *(float2*)(stage + (16 * bg + r16) * 8 + wv * 2) = make_float2(pA, pB);
        }

        __syncthreads();    // stage complete; h1 free for next macro

        // ---- cross-wave head sum + physics epilogue (own 16-batch slice, lanes 0-15) ----
        if (lane < 16) {
            const int b = wv * 16 + r16;
            const float4 s0 = *(const float4*)(stage + b * 8);       // w0A,w0B,w1A,w1B
            const float4 s1 = *(const float4*)(stage + b * 8 + 4);   // w2A,w2B,w3A,w3B
            const float a31_0 = (s0.x + s0.z) + bb31_0;
            const float a31_1 = (s0.y + s0.w) + bb31_1;
            const float a32_0 = (s1.x + s1.z) + bb32_0;
            const float a32_1 = (s1.y + s1.w) + bb32_1;
            const float s0v = 4.0f / (1.0f + __expf(-a32_0));
            const float s1v = 4.0f / (1.0f + __expf(-a32_1));
            const float px = fmaf(xc0, sd0, m0);
            const float py = fmaf(xc1, sd1, m1);
            const float th = fmaf(xc2, sd2, m2);
            const float v  = fmaf(xc3, sd3, m3);
            float sn, cs; __sincosf(th, &sn, &cs);
            const float dx = px - OBS_X, dy = py - OBS_Y;
            const float barrier     = dx * dx + dy * dy - RADIUS * RADIUS;
            const float barrier_dot = 2.f * dx * v * cs + 2.f * dy * v * sn;
            const float Lf2b = 2.f * v * v;
            const float G0 = 2.f * dx * v * sn - 2.f * dy * v * cs;   // -LgLfbu1
            const float G1 = -(2.f * dx * cs + 2.f * dy * sn);        // -LgLfbu2
            const float h  = Lf2b + (s0v + s1v) * barrier_dot + s0v * s1v * barrier;
            const float u00 = -a31_0, u01 = -a31_1;
            const float viol = G0 * u00 + G1 * u01 - h;
            const float gg   = G0 * G0 + G1 * G1;
            const float lam  = fmaxf(viol, 0.f) / (gg + 1e-12f);
            float2 uo = make_float2(fmaf(-lam, G0, u00), fmaf(-lam, G1, u01));
            ((float2*)out)[rowbase + b] = uo;
        }
    }
}

extern "C" void kernel_launch(void* const* d_in, const int* in_sizes, int n_in,
                              void* d_out, int out_size, void* d_ws, size_t ws_size,
                              hipStream_t stream) {
    const float* x     = (const float*)d_in[0];
    // d_in[1] = sgn (unused by the reference computation)
    const float* mean_ = (const float*)d_in[2];
    const float* std_  = (const float*)d_in[3];
    const float* w1    = (const float*)d_in[4];
    const float* b1    = (const float*)d_in[5];
    const float* w21   = (const float*)d_in[6];
    const float* b21   = (const float*)d_in[7];
    const float* w22   = (const float*)d_in[8];
    const float* b22   = (const float*)d_in[9];
    const float* w31   = (const float*)d_in[10];
    const float* b31   = (const float*)d_in[11];
    const float* w32   = (const float*)d_in[12];
    const float* b32   = (const float*)d_in[13];

    barriernet_fused<<<GRID, 256, 0, stream>>>(
        x, mean_, std_, w1, b1, w21, b21, w22, b22, w31, b31, w32, b32,
        (float*)d_out);
}